// Round 5
// baseline (1568.759 us; speedup 1.0000x reference)
//
#include <hip/hip_runtime.h>
#include <math.h>

#define N_IMG 32
#define P2304 2304
#define CIN 512
#define CMID 256
#define C2 128
#define LEV 128

typedef _Float16 half8 __attribute__((ext_vector_type(8)));
typedef float f32x16 __attribute__((ext_vector_type(16)));

// async global->LDS, 16B per lane; LDS dest = wave-uniform base + lane*16
__device__ __forceinline__ void async16(const void* gsrc, void* ldsdst){
  __builtin_amdgcn_global_load_lds(
      (const __attribute__((address_space(1))) void*)gsrc,
      (__attribute__((address_space(3))) void*)ldsdst, 16, 0, 0);
}

// ---------------- wave/block reduction helpers (wave = 64) ----------------
__device__ __forceinline__ float wredSum(float v){
#pragma unroll
  for (int o = 32; o > 0; o >>= 1) v += __shfl_down(v, o, 64);
  return v;
}
__device__ __forceinline__ float wredMax(float v){
#pragma unroll
  for (int o = 32; o > 0; o >>= 1) v = fmaxf(v, __shfl_down(v, o, 64));
  return v;
}
__device__ __forceinline__ float wredMin(float v){
#pragma unroll
  for (int o = 32; o > 0; o >>= 1) v = fminf(v, __shfl_down(v, o, 64));
  return v;
}

// ---------------- weight prepack: split f32 -> (hi, lo*2^11) f16 frags ----
__global__ void prep_w1_kernel(const float* __restrict__ w1,
                               uint4* __restrict__ Wh, uint4* __restrict__ Wl){
  int fid = blockIdx.x * 256 + threadIdx.x;     // 147456 frags
  int lam = fid & 63;
  int c32 = (fid >> 6) & 3;
  int cot = (fid >> 8) & 1;
  int kt  = fid >> 9;                           // 0..287
  int co = cot * 128 + c32 * 32 + (lam & 31);
  half8 vh, vl;
#pragma unroll
  for (int j = 0; j < 8; ++j){
    int k = kt * 16 + ((lam >> 5) << 3) + j;    // 0..4607
    int r = k >> 9;                             // tap
    int ci = k & 511;
    float v = w1[co * (CIN * 9) + ci * 9 + r];
    _Float16 h = (_Float16)v;
    vh[j] = h;
    vl[j] = (_Float16)((v - (float)h) * 2048.0f);
  }
  Wh[fid] = *(uint4*)&vh;
  Wl[fid] = *(uint4*)&vl;
}

__global__ void prep_w2_kernel(const float* __restrict__ w2,
                               uint4* __restrict__ Wh, uint4* __restrict__ Wl){
  int fid = blockIdx.x * 256 + threadIdx.x;     // 4096 frags
  int lam = fid & 63;
  int c32 = (fid >> 6) & 3;
  int kt  = fid >> 8;                           // 0..15
  int co = c32 * 32 + (lam & 31);
  half8 vh, vl;
#pragma unroll
  for (int j = 0; j < 8; ++j){
    int k = kt * 16 + ((lam >> 5) << 3) + j;    // 0..255
    float v = w2[co * CMID + k];
    _Float16 h = (_Float16)v;
    vh[j] = h;
    vl[j] = (_Float16)((v - (float)h) * 2048.0f);
  }
  Wh[fid] = *(uint4*)&vh;
  Wl[fid] = *(uint4*)&vl;
}

// s1 = g/sqrt(v+eps), t1 = b - m*s1
__global__ void prep_bn_kernel(const float* __restrict__ g1, const float* __restrict__ b1,
                               const float* __restrict__ m1, const float* __restrict__ v1,
                               float* __restrict__ s1, float* __restrict__ t1){
  int c = threadIdx.x;  // 256
  float s = g1[c] * (1.0f / sqrtf(v1[c] + 1e-5f));
  s1[c] = s;
  t1[c] = b1[c] - m1[c] * s;
}

// ---------------- pre-split x into padded fragment-contiguous f16 ---------
// xk[ n_l ][ cc=ci/8 ][ padp=(h+1)*50+(w+1) ][ 8 ci ]  (hi and lo arrays)
// pad ring (h or w == -1/48) is zero -> tap shifts need no clamp/mask.
__global__ void presplit_kernel(const float* __restrict__ x, int n0, int nimg,
                                uint4* __restrict__ xh, uint4* __restrict__ xl){
  int idx = blockIdx.x * 256 + threadIdx.x;
  if (idx >= nimg * 64 * 2500) return;
  int pp = idx % 2500;
  int cc = (idx / 2500) & 63;
  int nl = idx / (2500 * 64);
  int hrow = pp / 50;
  int h = hrow - 1, w = pp - hrow * 50 - 1;
  half8 vh = {0, 0, 0, 0, 0, 0, 0, 0};
  half8 vl = {0, 0, 0, 0, 0, 0, 0, 0};
  if ((unsigned)h < 48u && (unsigned)w < 48u){
    const float* src = x + ((size_t)(n0 + nl) * CIN + cc * 8) * P2304 + h * 48 + w;
#pragma unroll
    for (int j = 0; j < 8; ++j){
      float v = src[(size_t)j * P2304];
      _Float16 hh = (_Float16)v;
      vh[j] = hh;
      vl[j] = (_Float16)((v - (float)hh) * 2048.0f);
    }
  }
  xh[idx] = *(uint4*)&vh;
  xl[idx] = *(uint4*)&vl;
}

// ---------------- conv1: split-f16 MFMA, all-DMA staging ------------------
// 128co x 128p block, 4 waves (2ct x 2pt of 32x32x16 each), BK=32 dbuf LDS,
// one barrier/stage. A and B staged by global_load_lds (no VGPR round-trip,
// no convert VALU). B comes from pre-split padded xk, tap = index delta.
__global__ __launch_bounds__(256, 2) void conv1_dma_kernel(
    const uint4* __restrict__ xh, const uint4* __restrict__ xl,
    const uint4* __restrict__ Wh, const uint4* __restrict__ Wl,
    const float* __restrict__ s1, const float* __restrict__ t1,
    float* __restrict__ out, int n0)
{
  __shared__ _Float16 Abuf[2][2][2][2048];  // [buf][kf][hilo][c32*512+lam*8]
  __shared__ _Float16 Bbuf[2][2][2][2048];  // [buf][kf][hilo][p32*512+lam*8]
  const int t = threadIdx.x, lam = t & 63, g = t >> 6;
  const int bid = blockIdx.x;
  const int n_l = bid / 36, inner = bid % 36;
  const int pt_blk = inner % 18, cot = inner / 18;
  const int pbase = pt_blk * 128, cobase = cot * 128;
  const int khi = lam >> 5;
  const int pp = (g << 5) + (lam & 31);
  const int p = pbase + pp;
  const int ph = p / 48, pw = p - ph * 48;
  const int padbase = (ph + 1) * 50 + pw + 1;
  const int nbase = n_l * 64 * 2500;

  f32x16 acc_hh[2][2], acc_x[2][2];
#pragma unroll
  for (int a = 0; a < 2; ++a)
#pragma unroll
    for (int b = 0; b < 2; ++b){
#pragma unroll
      for (int e = 0; e < 16; ++e){ acc_hh[a][b][e] = 0.f; acc_x[a][b][e] = 0.f; }
    }

#define STG(SV, BF)                                                           \
  {                                                                           \
    int s_ = (SV);                                                            \
    int r_ = s_ >> 4;                                                         \
    int r3_ = r_ / 3;                                                         \
    int dlt = (r3_ - 1) * 50 + (r_ - r3_ * 3 - 1);                            \
    _Pragma("unroll")                                                         \
    for (int kf = 0; kf < 2; ++kf){                                           \
      int kt = 2 * s_ + kf;                                                   \
      int fi = ((kt * 2 + cot) * 4 + g) * 64 + lam;                           \
      async16(Wh + fi, &Abuf[BF][kf][0][g * 512]);                            \
      async16(Wl + fi, &Abuf[BF][kf][1][g * 512]);                            \
      int cc = ((s_ & 15) << 2) + (kf << 1) + khi;                            \
      int bi = nbase + cc * 2500 + padbase + dlt;                             \
      async16(xh + bi, &Bbuf[BF][kf][0][g * 512]);                            \
      async16(xl + bi, &Bbuf[BF][kf][1][g * 512]);                            \
    }                                                                         \
  }

#define CMP(CUR, KF)                                                          \
  {                                                                           \
    const int ct0 = (g & 1) * 2, pt0 = (g >> 1) * 2;                          \
    half8 fAh[2], fAl[2], fBh[2], fBl[2];                                     \
    _Pragma("unroll")                                                         \
    for (int a = 0; a < 2; ++a){                                              \
      fAh[a] = *(half8*)&Abuf[CUR][KF][0][(ct0 + a) * 512 + lam * 8];         \
      fAl[a] = *(half8*)&Abuf[CUR][KF][1][(ct0 + a) * 512 + lam * 8];         \
      fBh[a] = *(half8*)&Bbuf[CUR][KF][0][(pt0 + a) * 512 + lam * 8];         \
      fBl[a] = *(half8*)&Bbuf[CUR][KF][1][(pt0 + a) * 512 + lam * 8];         \
    }                                                                         \
    _Pragma("unroll")                                                         \
    for (int a = 0; a < 2; ++a)                                               \
      _Pragma("unroll")                                                       \
      for (int b = 0; b < 2; ++b){                                            \
        acc_hh[a][b] = __builtin_amdgcn_mfma_f32_32x32x16_f16(                \
            fAh[a], fBh[b], acc_hh[a][b], 0, 0, 0);                           \
        acc_x[a][b] = __builtin_amdgcn_mfma_f32_32x32x16_f16(                 \
            fAh[a], fBl[b], acc_x[a][b], 0, 0, 0);                            \
        acc_x[a][b] = __builtin_amdgcn_mfma_f32_32x32x16_f16(                 \
            fAl[a], fBh[b], acc_x[a][b], 0, 0, 0);                            \
      }                                                                       \
  }

  STG(0, 0);
  __syncthreads();
  for (int s = 0; s < 144; ++s){
    const int cur = s & 1;
    if (s + 1 < 144) STG(s + 1, cur ^ 1);
    CMP(cur, 0);
    CMP(cur, 1);
    __syncthreads();
  }
#undef STG
#undef CMP

  // epilogue: combine hi/lo, bn + leaky, store f32
#pragma unroll
  for (int a = 0; a < 2; ++a){
    const int ctile = (g & 1) * 2 + a;
#pragma unroll
    for (int b = 0; b < 2; ++b){
      const int ptile = (g >> 1) * 2 + b;
      const int pg = pbase + ptile * 32 + (lam & 31);
#pragma unroll
      for (int rg = 0; rg < 16; ++rg){
        const int row = (rg & 3) + 8 * (rg >> 2) + 4 * (lam >> 5);
        const int co = cobase + ctile * 32 + row;
        float val = acc_hh[a][b][rg] + acc_x[a][b][rg] * (1.0f / 2048.0f);
        val = val * s1[co] + t1[co];
        val = val > 0.f ? val : 0.01f * val;
        out[((size_t)(n0 + n_l) * CMID + co) * P2304 + pg] = val;
      }
    }
  }
}

// ---------------- conv2 (1x1): R4-style pipelined kernel ------------------
template<int R, int CPT, int COTN, bool BN>
__global__ __launch_bounds__(256, 2) void conv_mfma_kernel(
    const float* __restrict__ in, const uint4* __restrict__ Wh, const uint4* __restrict__ Wl,
    const float* __restrict__ s1, const float* __restrict__ t1, float* __restrict__ out)
{
  __shared__ _Float16 Abuf[2][2][2][2048];
  __shared__ _Float16 Bbuf[2][2][2][2048];
  const int t = threadIdx.x;
  const int lam = t & 63;
  const int g = t >> 6;

  int n, pt_blk, cot;
  if (COTN == 2){
    int xcd = blockIdx.x & 7;
    int rest = blockIdx.x >> 3;
    n = xcd * 4 + rest / 36;
    int inner = rest % 36;
    pt_blk = inner % 18;
    cot = inner / 18;
  } else {
    pt_blk = blockIdx.x % 18;
    cot = 0;
    n = blockIdx.x / 18;
  }
  const int pbase = pt_blk * 128;
  const int cobase = cot * 128;

  const int khi = lam >> 5;
  const int pp = (g << 5) + (lam & 31);
  const int p = pbase + pp;
  const int ph = p / 48, pw = p - ph * 48;
  const float* in_n = in + (size_t)n * CPT * P2304;

  const int S = (R * CPT) / 32;
  const int KTPT = CPT / 16;

  f32x16 acc_hh[2][2], acc_x[2][2];
#pragma unroll
  for (int a = 0; a < 2; ++a)
#pragma unroll
    for (int b = 0; b < 2; ++b){
#pragma unroll
      for (int e = 0; e < 16; ++e){ acc_hh[a][b][e] = 0.f; acc_x[a][b][e] = 0.f; }
    }

  uint4 rAh[2], rAl[2];
  float rB[16];
  bool vmask;

#define ISSUE(SV)                                                             \
  {                                                                           \
    int s_ = (SV);                                                            \
    _Pragma("unroll")                                                         \
    for (int kf = 0; kf < 2; ++kf){                                           \
      int fi = (((2 * s_ + kf) * COTN + cot) * 4 + g) * 64 + lam;             \
      rAh[kf] = Wh[fi];                                                       \
      rAl[kf] = Wl[fi];                                                       \
    }                                                                         \
    int r_ = (R == 1) ? 0 : ((2 * s_) / KTPT);                                \
    int cbase_ = ((2 * s_) % KTPT) * 16;                                      \
    int dh_ = (R == 1) ? 0 : (r_ / 3 - 1);                                    \
    int dw_ = (R == 1) ? 0 : (r_ - (r_ / 3) * 3 - 1);                         \
    int hh_ = ph + dh_, ww_ = pw + dw_;                                       \
    vmask = ((unsigned)hh_ < 48u) & ((unsigned)ww_ < 48u);                    \
    int hc_ = min(max(hh_, 0), 47), wc_ = min(max(ww_, 0), 47);               \
    const float* src_ = in_n + hc_ * 48 + wc_                                 \
                        + (size_t)(cbase_ + khi * 8) * P2304;                 \
    _Pragma("unroll")                                                         \
    for (int kf = 0; kf < 2; ++kf)                                            \
      _Pragma("unroll")                                                       \
      for (int j = 0; j < 8; ++j)                                             \
        rB[kf * 8 + j] = src_[(kf * 16 + j) * P2304];                         \
  }

#define STASH(NXT)                                                            \
  {                                                                           \
    _Pragma("unroll")                                                         \
    for (int kf = 0; kf < 2; ++kf){                                           \
      *(uint4*)&Abuf[NXT][kf][0][t * 8] = rAh[kf];                            \
      *(uint4*)&Abuf[NXT][kf][1][t * 8] = rAl[kf];                            \
      half8 vh, vl;                                                           \
      _Pragma("unroll")                                                       \
      for (int j = 0; j < 8; ++j){                                            \
        float v = vmask ? rB[kf * 8 + j] : 0.0f;                              \
        _Float16 h = (_Float16)v;                                             \
        vh[j] = h;                                                            \
        vl[j] = (_Float16)((v - (float)h) * 2048.0f);                        \
      }                                                                       \
      *(half8*)&Bbuf[NXT][kf][0][t * 8] = vh;                                 \
      *(half8*)&Bbuf[NXT][kf][1][t * 8] = vl;                                 \
    }                                                                         \
  }

#define COMPUTE(CUR, KF)                                                      \
  {                                                                           \
    const int ct0 = (g & 1) * 2, pt0 = (g >> 1) * 2;                          \
    half8 fAh[2], fAl[2], fBh[2], fBl[2];                                     \
    _Pragma("unroll")                                                         \
    for (int a = 0; a < 2; ++a){                                              \
      fAh[a] = *(half8*)&Abuf[CUR][KF][0][(ct0 + a) * 512 + lam * 8];         \
      fAl[a] = *(half8*)&Abuf[CUR][KF][1][(ct0 + a) * 512 + lam * 8];         \
      fBh[a] = *(half8*)&Bbuf[CUR][KF][0][(pt0 + a) * 512 + lam * 8];         \
      fBl[a] = *(half8*)&Bbuf[CUR][KF][1][(pt0 + a) * 512 + lam * 8];         \
    }                                                                         \
    _Pragma("unroll")                                                         \
    for (int a = 0; a < 2; ++a)                                               \
      _Pragma("unroll")                                                       \
      for (int b = 0; b < 2; ++b){                                            \
        acc_hh[a][b] = __builtin_amdgcn_mfma_f32_32x32x16_f16(                \
            fAh[a], fBh[b], acc_hh[a][b], 0, 0, 0);                           \
        acc_x[a][b] = __builtin_amdgcn_mfma_f32_32x32x16_f16(                 \
            fAh[a], fBl[b], acc_x[a][b], 0, 0, 0);                            \
        acc_x[a][b] = __builtin_amdgcn_mfma_f32_32x32x16_f16(                 \
            fAl[a], fBh[b], acc_x[a][b], 0, 0, 0);                            \
      }                                                                       \
  }

  ISSUE(0);
  STASH(0);
  __syncthreads();

  for (int s = 0; s < S; ++s){
    const int cur = s & 1, nxt = cur ^ 1;
    const bool more = (s + 1 < S);
    if (more) ISSUE(s + 1);
    COMPUTE(cur, 0);
    if (more) STASH(nxt);
    COMPUTE(cur, 1);
    __syncthreads();
  }
#undef ISSUE
#undef STASH
#undef COMPUTE

  const int M = COTN * 128;
#pragma unroll
  for (int a = 0; a < 2; ++a){
    const int ctile = (g & 1) * 2 + a;
#pragma unroll
    for (int b = 0; b < 2; ++b){
      const int ptile = (g >> 1) * 2 + b;
      const int pg = pbase + ptile * 32 + (lam & 31);
#pragma unroll
      for (int rg = 0; rg < 16; ++rg){
        const int row = (rg & 3) + 8 * (rg >> 2) + 4 * (lam >> 5);
        const int co = cobase + ctile * 32 + row;
        float val = acc_hh[a][b][rg] + acc_x[a][b][rg] * (1.0f / 2048.0f);
        if (BN){
          val = val * s1[co] + t1[co];
          val = val > 0.f ? val : 0.01f * val;
        }
        out[((size_t)n * M + co) * P2304 + pg] = val;
      }
    }
  }
}

// ---------------- x_ave ----------------
__global__ void xave_kernel(const float* __restrict__ x2, float* __restrict__ xave){
  __shared__ float red[4];
  int nc = blockIdx.x, t = threadIdx.x;
  const float* row = x2 + nc * P2304;
  float s = 0.f;
#pragma unroll
  for (int i = 0; i < 9; i++) s += row[t + 256 * i];
  float w = wredSum(s);
  if ((t & 63) == 0) red[t >> 6] = w;
  __syncthreads();
  if (t == 0) xave[nc] = (red[0] + red[1] + red[2] + red[3]) * (1.0f / 2304.0f);
}

__global__ void xan_kernel(const float* __restrict__ xave, float* __restrict__ xan){
  __shared__ float red[2];
  int n = blockIdx.x, t = threadIdx.x; // 128 threads
  float v = xave[n * 128 + t];
  float w = wredSum(v * v);
  if ((t & 63) == 0) red[t >> 6] = w;
  __syncthreads();
  float norm = fmaxf(sqrtf(red[0] + red[1]), 1e-12f);
  xan[n * 128 + t] = v / norm;
}

__global__ void cos_kernel(const float* __restrict__ x2, const float* __restrict__ xan,
                           float* __restrict__ cosb){
  int idx = blockIdx.x * 256 + threadIdx.x;
  if (idx >= N_IMG * P2304) return;
  int n = idx / P2304;
  int p = idx - n * P2304;
  const float* xp = x2 + n * C2 * P2304 + p;
  const float* an = xan + n * 128;
  float dot = 0.f, ss = 0.f;
  for (int c = 0; c < 128; c++){
    float v = xp[c * P2304];
    dot += an[c] * v;
    ss  += v * v;
  }
  cosb[idx] = dot / fmaxf(sqrtf(ss), 1e-12f);
}

__global__ void lbp_kernel(const float* __restrict__ cosb, float* __restrict__ code,
                           float* __restrict__ qlv){
  __shared__ float red[4];
  int n = blockIdx.x;
  int l = threadIdx.x;
  int ir = l >> 4, ic = l & 15;
  const float* cn = cosb + n * P2304;
  float cs4 = cn[(16 + ir) * 48 + (16 + ic)];
  const float wts[9] = {1.f, 2.f, 4.f, 8.f, 0.f, 16.f, 32.f, 64.f, 128.f};
  float codev = 0.f;
#pragma unroll
  for (int j = 0; j < 9; j++){
    int jr = j / 3, jc = j - 3 * (j / 3);
    float vv = cn[(jr * 16 + ir) * 48 + (jc * 16 + ic)];
    if (vv > cs4) codev += wts[j];
  }
  float w;
  w = wredMin(codev);
  if ((l & 63) == 0) red[l >> 6] = w;
  __syncthreads();
  float mn = fminf(fminf(red[0], red[1]), fminf(red[2], red[3]));
  __syncthreads();
  w = wredMax(codev);
  if ((l & 63) == 0) red[l >> 6] = w;
  __syncthreads();
  float mx = fmaxf(fmaxf(red[0], red[1]), fmaxf(red[2], red[3]));
  __syncthreads();
  float cd = (codev - mn) / (mx - mn);
  w = wredMin(cd);
  if ((l & 63) == 0) red[l >> 6] = w;
  __syncthreads();
  float cmin = fminf(fminf(red[0], red[1]), fminf(red[2], red[3]));
  __syncthreads();
  w = wredMax(cd);
  if ((l & 63) == 0) red[l >> 6] = w;
  __syncthreads();
  float cmax = fmaxf(fmaxf(red[0], red[1]), fmaxf(red[2], red[3]));
  code[n * 256 + l] = cd;
  if (l < 128){
    float tmp = (float)(2 * l + 1) * (1.0f / 256.0f);
    qlv[n * 128 + l] = tmp * (cmax - cmin) + cmin;
  }
}

__global__ void quant_kernel(const float* __restrict__ code, const float* __restrict__ qlv,
                             float* __restrict__ quantT){
  __shared__ float cs[256];
  __shared__ float qs[128];
  int n = blockIdx.x, t = threadIdx.x;
  cs[t] = code[n * 256 + t];
  if (t < 128) qs[t] = qlv[n * 128 + t];
  __syncthreads();
  float thr = 1.0f - (qs[1] - qs[0]);
  float* dst = quantT + n * LEV * 256;
#pragma unroll 4
  for (int i = 0; i < 128; i++){
    int v = t + 256 * i;
    int lv = v >> 8;
    int p = v & 255;
    float qq = 1.0f - fabsf(qs[lv] - cs[p]);
    dst[v] = (qq > thr) ? qq : 0.f;
  }
}

__global__ void sta_kernel(const float* __restrict__ quantT, float* __restrict__ sta){
  __shared__ float red[2];
  int n = blockIdx.x, i = threadIdx.x; // 128 threads
  const float* qr = quantT + (n * LEV + i) * 256;
  float s = 0.f;
  for (int p = 0; p < 256; p++) s += qr[p];
  float w = wredSum(s);
  if ((i & 63) == 0) red[i >> 6] = w;
  __syncthreads();
  float tot = red[0] + red[1];
  sta[n * 128 + i] = s / tot;
}

__global__ void h1_kernel(const float* __restrict__ f1w, const float* __restrict__ qlv,
                          const float* __restrict__ sta, float* __restrict__ h1){
  int idx = blockIdx.x * 256 + threadIdx.x;
  if (idx >= N_IMG * 64 * 128) return;
  int l = idx & 127;
  int n = idx >> 13;
  int o = (idx >> 7) & 63;
  float a = f1w[o * 2] * qlv[n * 128 + l] + f1w[o * 2 + 1] * sta[n * 128 + l];
  h1[idx] = a > 0.f ? a : 0.01f * a;
}

__global__ void gemm_w_kernel(const float* __restrict__ Wm, const float* __restrict__ B,
                              float* __restrict__ Cout, int Cdim, int O, int total, int mode,
                              const float* __restrict__ g, const float* __restrict__ bb,
                              const float* __restrict__ mm, const float* __restrict__ vv){
  int idx = blockIdx.x * 256 + threadIdx.x;
  if (idx >= total) return;
  int per_n = (O >> 2) << 7;
  int n = idx / per_n;
  int rem = idx - n * per_n;
  int o0 = (rem >> 7) << 2;
  int l = rem & 127;
  const float* Bn = B + (n * Cdim) * 128 + l;
  const float* w0 = Wm + (o0 + 0) * Cdim;
  const float* w1 = Wm + (o0 + 1) * Cdim;
  const float* w2 = Wm + (o0 + 2) * Cdim;
  const float* w3 = Wm + (o0 + 3) * Cdim;
  float a0 = 0, a1 = 0, a2 = 0, a3 = 0;
  for (int c = 0; c < Cdim; c++){
    float bv = Bn[c * 128];
    a0 += w0[c] * bv; a1 += w1[c] * bv; a2 += w2[c] * bv; a3 += w3[c] * bv;
  }
  float av[4] = {a0, a1, a2, a3};
#pragma unroll
  for (int j = 0; j < 4; j++){
    int o = o0 + j;
    float val = av[j];
    if (mode == 1){
      float s = g[o] * (1.0f / sqrtf(vv[o] + 1e-5f));
      val = (val - mm[o]) * s + bb[o];
      val = fmaxf(val, 0.f);
    }
    Cout[(n * O + o) * 128 + l] = val;
  }
}

__global__ void concat_kernel(const float* __restrict__ h2, const float* __restrict__ xave,
                              float* __restrict__ s){
  int idx = blockIdx.x * 256 + threadIdx.x;
  if (idx >= N_IMG * 256 * 128) return;
  int l = idx & 127;
  int c = (idx >> 7) & 255;
  int n = idx >> 15;
  s[idx] = (c < 128) ? h2[(n * 128 + c) * 128 + l] : xave[n * 128 + (c - 128)];
}

__global__ void attn_sc_kernel(const float* __restrict__ k, const float* __restrict__ q,
                               float* __restrict__ sc){
  int idx = blockIdx.x * 256 + threadIdx.x;
  if (idx >= N_IMG * 32 * 128) return;
  int m = idx & 127;
  int l0 = ((idx >> 7) & 31) << 2;
  int n = idx >> 12;
  const float* kn = k + n * 256 * 128;
  const float* qn = q + n * 256 * 128 + m;
  float a0 = 0, a1 = 0, a2 = 0, a3 = 0;
  for (int c = 0; c < 256; c++){
    float qv = qn[c * 128];
    const float* kr = kn + c * 128 + l0;
    a0 += kr[0] * qv; a1 += kr[1] * qv; a2 += kr[2] * qv; a3 += kr[3] * qv;
  }
  float* dst = sc + (n * 128 + l0) * 128 + m;
  dst[0] = a0; dst[128] = a1; dst[256] = a2; dst[384] = a3;
}

__global__ void softmax_kernel(float* __restrict__ sc){
  __shared__ float red[2];
  int row = blockIdx.x;
  int t = threadIdx.x; // 128
  float v = sc[row * 128 + t];
  float w = wredMax(v);
  if ((t & 63) == 0) red[t >> 6] = w;
  __syncthreads();
  float mx = fmaxf(red[0], red[1]);
  float e = expf(v - mx);
  float s = wredSum(e);
  __syncthreads();
  if ((t & 63) == 0) red[t >> 6] = s;
  __syncthreads();
  sc[row * 128 + t] = e / (red[0] + red[1]);
}

__global__ void transpose_sc_kernel(const float* __restrict__ sc, float* __restrict__ scT){
  int idx = blockIdx.x * 256 + threadIdx.x;
  if (idx >= N_IMG * 128 * 128) return;
  int l = idx & 127;
  int m = (idx >> 7) & 127;
  int n = idx >> 14;
  scT[idx] = sc[(n * 128 + l) * 128 + m];
}

__global__ void attn_f_kernel(const float* __restrict__ vb, const float* __restrict__ scT,
                              float* __restrict__ f){
  int idx = blockIdx.x * 256 + threadIdx.x;
  if (idx >= N_IMG * 64 * 128) return;
  int l = idx & 127;
  int c0 = ((idx >> 7) & 63) << 2;
  int n = idx >> 13;
  const float* vn = vb + (n * 256 + c0) * 128;
  const float* sn = scT + n * 128 * 128 + l;
  float a0 = 0, a1 = 0, a2 = 0, a3 = 0;
  for (int m = 0; m < 128; m++){
    float sv = sn[m * 128];
    a0 += vn[m] * sv; a1 += vn[128 + m] * sv; a2 += vn[256 + m] * sv; a3 += vn[384 + m] * sv;
  }
  float* dst = f + (n * 256 + c0) * 128 + l;
  dst[0] = a0; dst[128] = a1; dst[256] = a2; dst[384] = a3;
}

__global__ void final_kernel(const float* __restrict__ g, const float* __restrict__ quantT,
                             float* __restrict__ outs){
  int idx = blockIdx.x * 256 + threadIdx.x;
  if (idx >= N_IMG * 64 * 256) return;
  int p = idx & 255;
  int c0 = ((idx >> 8) & 63) << 2;
  int n = idx >> 14;
  const float* gn = g + (n * 256 + c0) * 128;
  const float* qn = quantT + (n * LEV) * 256 + p;
  float a0 = 0, a1 = 0, a2 = 0, a3 = 0;
  for (int lv = 0; lv < 128; lv++){
    float qv = qn[lv * 256];
    a0 += gn[lv] * qv; a1 += gn[128 + lv] * qv; a2 += gn[256 + lv] * qv; a3 += gn[384 + lv] * qv;
  }
  float* dst = outs + (n * 256 + c0) * 256 + p;
  dst[0] = a0; dst[256] = a1; dst[512] = a2; dst[768] = a3;
}

__global__ void resize_kernel(const float* __restrict__ outs, float* __restrict__ dout){
  int idx = blockIdx.x * 256 + threadIdx.x;
  if (idx >= N_IMG * 256 * P2304) return;
  int ow = idx % 48;
  int tmp = idx / 48;
  int oh = tmp % 48;
  int nc = tmp / 48;
  const float* src = outs + nc * 256;
  float fy = oh * (15.0f / 47.0f);
  float fx = ow * (15.0f / 47.0f);
  int y0 = (int)fy;
  int x0 = (int)fx;
  int y1 = min(y0 + 1, 15);
  int x1 = min(x0 + 1, 15);
  float wy = fy - (float)y0;
  float wx = fx - (float)x0;
  float v00 = src[y0 * 16 + x0], v01 = src[y0 * 16 + x1];
  float v10 = src[y1 * 16 + x0], v11 = src[y1 * 16 + x1];
  dout[idx] = v00 * (1.f - wy) * (1.f - wx) + v01 * (1.f - wy) * wx
            + v10 * wy * (1.f - wx) + v11 * wy * wx;
}

// ---------------- launcher ----------------
extern "C" void kernel_launch(void* const* d_in, const int* in_sizes, int n_in,
                              void* d_out, int out_size, void* d_ws, size_t ws_size,
                              hipStream_t stream)
{
  const float* x       = (const float*)d_in[0];
  const float* conv1_w = (const float*)d_in[1];
  const float* bn1_g   = (const float*)d_in[2];
  const float* bn1_b   = (const float*)d_in[3];
  const float* bn1_m   = (const float*)d_in[4];
  const float* bn1_v   = (const float*)d_in[5];
  const float* conv2_w = (const float*)d_in[6];
  const float* f1_w    = (const float*)d_in[7];
  const float* f2_w    = (const float*)d_in[8];
  const float* f2_g    = (const float*)d_in[9];
  const float* f2_b    = (const float*)d_in[10];
  const float* f2_m    = (const float*)d_in[11];
  const float* f2_v    = (const float*)d_in[12];
  const float* out1_w  = (const float*)d_in[13];
  const float* out1_g  = (const float*)d_in[14];
  const float* out1_b  = (const float*)d_in[15];
  const float* out1_m  = (const float*)d_in[16];
  const float* out1_v  = (const float*)d_in[17];
  const float* k_w     = (const float*)d_in[18];
  const float* q_w     = (const float*)d_in[19];
  const float* v_w     = (const float*)d_in[20];
  const float* out_w   = (const float*)d_in[21];
  const float* out_g   = (const float*)d_in[22];
  const float* out_b   = (const float*)d_in[23];
  const float* out_m   = (const float*)d_in[24];
  const float* out_v   = (const float*)d_in[25];

  float* ws = (float*)d_ws;
  float* dout = (float*)d_out;

  // workspace-adaptive image chunking for the pre-split buffer
  // floats needed = y(18874368) + max(x2 9437184, nimg*1280000) + weights(1212928)
  size_t favail = ws_size >> 2;
  int nimg = 4;                         // 29,524,480 f = proven-safe 118.1 MB
  if (favail >= 61047296) nimg = 32;
  else if (favail >= 40567296) nimg = 16;
  else if (favail >= 30327296) nimg = 8;
  const int NC = 32 / nimg;

  const size_t F_Y = 18874368;
  size_t xkF = (size_t)nimg * 1280000;           // both hi+lo arrays
  size_t reg2 = xkF > 9437184 ? xkF : (size_t)9437184;

  float* w_y   = ws;                   // y: 32x256x2304 f32
  float* w_xk  = ws + F_Y;             // pre-split chunk; x2 aliases here later
  float* w_x2  = w_xk;
  uint4* xkh   = (uint4*)w_xk;
  uint4* xkl   = xkh + (size_t)nimg * 160000;
  float* w_wbk = ws + F_Y + reg2;
  float* w_W1h = w_wbk;                // 589824 f
  float* w_W1l = w_wbk + 589824;
  float* w_W2h = w_wbk + 1179648;      // 16384 f
  float* w_W2l = w_wbk + 1196032;
  float* w_s1  = w_wbk + 1212416;      // 256
  float* w_t1  = w_wbk + 1212672;      // 256 (block total 1212928)

  // small buffers reuse the y region (only written after conv2 consumed y)
  float* w_xave = w_y + 0;
  float* w_xan  = w_y + 4096;
  float* w_cos  = w_y + 8192;
  float* w_code = w_y + 81920;
  float* w_qlv  = w_y + 90112;
  float* w_sta  = w_y + 94208;
  float* w_quant= w_y + 98304;
  float* w_h1   = w_y + 1146880;
  float* w_h2   = w_y + 1409024;
  float* w_s    = w_y + 1933312;
  float* w_k    = w_y + 2981888;
  float* w_q    = w_y + 4030464;
  float* w_v    = w_y + 5079040;
  float* w_sc   = w_y + 6127616;
  float* w_scT  = w_y + 6651904;
  float* w_f    = w_y + 7176192;
  float* w_g    = w_y + 8224768;
  float* w_outs = w_y + 9273344;
  float* w_s2   = w_y + 11370496;

  prep_w1_kernel<<<576, 256, 0, stream>>>(conv1_w, (uint4*)w_W1h, (uint4*)w_W1l);
  prep_w2_kernel<<<16, 256, 0, stream>>>(conv2_w, (uint4*)w_W2h, (uint4*)w_W2l);
  prep_bn_kernel<<<1, 256, 0, stream>>>(bn1_g, bn1_b, bn1_m, bn1_v, w_s1, w_t1);

  for (int c = 0; c < NC; ++c){
    presplit_kernel<<<nimg * 625, 256, 0, stream>>>(x, c * nimg, nimg, xkh, xkl);
    conv1_dma_kernel<<<nimg * 36, 256, 0, stream>>>(
        xkh, xkl, (const uint4*)w_W1h, (const uint4*)w_W1l, w_s1, w_t1, w_y, c * nimg);
  }
  conv_mfma_kernel<1, 256, 1, false><<<576, 256, 0, stream>>>(
      w_y, (const uint4*)w_W2h, (const uint4*)w_W2l, w_s1, w_t1, w_x2);

  xave_kernel<<<4096, 256, 0, stream>>>(w_x2, w_xave);
  xan_kernel<<<32, 128, 0, stream>>>(w_xave, w_xan);
  cos_kernel<<<288, 256, 0, stream>>>(w_x2, w_xan, w_cos);
  lbp_kernel<<<32, 256, 0, stream>>>(w_cos, w_code, w_qlv);
  quant_kernel<<<32, 256, 0, stream>>>(w_code, w_qlv, w_quant);
  sta_kernel<<<32, 128, 0, stream>>>(w_quant, w_sta);
  h1_kernel<<<1024, 256, 0, stream>>>(f1_w, w_qlv, w_sta, w_h1);
  gemm_w_kernel<<<512, 256, 0, stream>>>(f2_w, w_h1, w_h2, 64, 128, N_IMG * 32 * 128, 1,
                                         f2_g, f2_b, f2_m, f2_v);
  concat_kernel<<<4096, 256, 0, stream>>>(w_h2, w_xave, w_s);
  gemm_w_kernel<<<1024, 256, 0, stream>>>(out1_w, w_s, w_s2, 256, 256, N_IMG * 64 * 128, 1,
                                          out1_g, out1_b, out1_m, out1_v);
  gemm_w_kernel<<<1024, 256, 0, stream>>>(k_w, w_s2, w_k, 256, 256, N_IMG * 64 * 128, 0,
                                          nullptr, nullptr, nullptr, nullptr);
  gemm_w_kernel<<<1024, 256, 0, stream>>>(q_w, w_s2, w_q, 256, 256, N_IMG * 64 * 128, 0,
                                          nullptr, nullptr, nullptr, nullptr);
  gemm_w_kernel<<<1024, 256, 0, stream>>>(v_w, w_s2, w_v, 256, 256, N_IMG * 64 * 128, 0,
                                          nullptr, nullptr, nullptr, nullptr);
  attn_sc_kernel<<<512, 256, 0, stream>>>(w_k, w_q, w_sc);
  softmax_kernel<<<4096, 128, 0, stream>>>(w_sc);
  transpose_sc_kernel<<<2048, 256, 0, stream>>>(w_sc, w_scT);
  attn_f_kernel<<<1024, 256, 0, stream>>>(w_v, w_scT, w_f);
  gemm_w_kernel<<<1024, 256, 0, stream>>>(out_w, w_f, w_g, 256, 256, N_IMG * 64 * 128, 1,
                                          out_g, out_b, out_m, out_v);
  final_kernel<<<2048, 256, 0, stream>>>(w_g, w_quant, w_outs);
  resize_kernel<<<73728, 256, 0, stream>>>(w_outs, dout);
}